// Round 10
// baseline (301.532 us; speedup 1.0000x reference)
//
#include <hip/hip_runtime.h>

// HSTU block, B=2 S=2048 D=1024 H=8 head=64 L=2. Inputs/outputs fp32.
// ws (62 MB): xf f32(16M) | h bf16(8M; aliased by kpack 4M + vpack 4M)
//  | udot bf16(4M) | projh bf16(16M) | uvqkT bf16(8M) | owh bf16(2M)
//  | opart bf16 2 z-slices (8M)
// h / uvqkT / udot / owh are stored FRAGMENT-PACKED (chunk-major):
//   X_pk[(c*MG + mg)*512 + quad*128 + l15*8 + k] = X[mg*16 + l15][c*32 + quad*8 + k]
#define B_ 2
#define S_ 2048
#define D_ 1024
#define H_ 8
#define L_ 2
#define P_ 2048   // proj dim
#define F_ 512    // DL*H
#define R_ (B_*S_)

typedef unsigned short u16;
typedef unsigned int u32;
typedef __bf16 bf16;
typedef bf16 bf16x8 __attribute__((ext_vector_type(8)));
typedef short short8 __attribute__((ext_vector_type(8)));
typedef float v4f __attribute__((ext_vector_type(4)));

__device__ __forceinline__ float silu_fast(float x){
  float e = __expf(-x);
  return x * __builtin_amdgcn_rcpf(1.0f + e);
}
__device__ __forceinline__ float bf2f(u16 u){
  union { u32 i; float f; } x; x.i = ((u32)u) << 16; return x.f;
}
__device__ __forceinline__ u16 f2bfu(float f){
  union { float f; u32 i; } x; x.f = f;
  u32 r = x.i + 0x7fff + ((x.i >> 16) & 1);   // RNE
  return (u16)(r >> 16);
}

// ---- o_w (L,D,F) f32 -> owh fragment-packed bf16 ----
__global__ __launch_bounds__(256) void cvt_owh_kernel(const float* __restrict__ src, u16* __restrict__ dst){
  int i = (blockIdx.x * 256 + threadIdx.x) * 4;    // over L*D*F
  float4 v = *(const float4*)(src + i);
  int l = i >> 19;                                  // D*F = 2^19
  int rem = i & ((1 << 19) - 1);
  int n = rem >> 9, f = rem & 511;                  // F = 2^9
  int ng = n >> 4, l15 = n & 15;
  int c = f >> 5, q = (f >> 3) & 3, j = f & 7;      // j in {0,4}
  ushort4 o; o.x = f2bfu(v.x); o.y = f2bfu(v.y); o.z = f2bfu(v.z); o.w = f2bfu(v.w);
  // per layer: 16 chunks x 64 ngroups
  *(ushort4*)(dst + (size_t)l * D_ * F_ + ((size_t)(c*64 + ng))*512 + q*128 + l15*8 + j) = o;
}

// ---- uvqk (L,D,P) f32 -> uvqkT fragment-packed bf16 (32 chunks x 128 ngroups) ----
// Each 32x32 tile's packed destination is ONE contiguous 2KB region
// (base = (C0*128 + ng0)*512, ng0 = p0/16, C0 = d0/32): 256 threads gather
// 4 values each from the LDS tile and store ushort4 fully coalesced.
__global__ __launch_bounds__(256) void cvt_uvqkT_kernel(const float* __restrict__ uvqk, u16* __restrict__ ot){
  __shared__ float t[32][33];
  int l = blockIdx.z;
  int p0 = blockIdx.x * 32, d0 = blockIdx.y * 32;
  int tx = threadIdx.x & 31, ty = threadIdx.x >> 5;   // ty: 8 rows/pass
  const float* src = uvqk + ((size_t)l * D_ + d0) * P_ + p0;
  #pragma unroll
  for (int s = 0; s < 4; s++)
    t[ty + s*8][tx] = src[(size_t)(ty + s*8) * P_ + tx];   // t[d_local][p_local]
  __syncthreads();
  int o = threadIdx.x * 4;                 // packed offset in [0,1024)
  int ngl = o >> 9, rem = o & 511;
  int q = rem >> 7, l15 = (rem >> 3) & 15, j0 = rem & 7;   // j0 in {0,4}
  int pl = ngl*16 + l15;
  ushort4 ov;
  ov.x = f2bfu(t[q*8 + j0 + 0][pl]);
  ov.y = f2bfu(t[q*8 + j0 + 1][pl]);
  ov.z = f2bfu(t[q*8 + j0 + 2][pl]);
  ov.w = f2bfu(t[q*8 + j0 + 3][pl]);
  size_t base = ((size_t)(blockIdx.y*128 + blockIdx.x*2))*512;
  *(ushort4*)(ot + (size_t)l * P_ * D_ + base + o) = ov;
}

// ---- pack K and V tiles into fragment-linear order ----
__global__ __launch_bounds__(256) void kvpack_kernel(const u16* __restrict__ projh,
    u16* __restrict__ kpack, u16* __restrict__ vpack){
  __shared__ u16 tls[64*72];
  int t = blockIdx.x, t0 = t * 64;
  int bh = blockIdx.y;
  int b = bh >> 3, hh = bh & 7;
  int tid = threadIdx.x;
  const size_t bS = (size_t)b * S_;
  const int voff = F_ + hh*64, koff = 3*F_ + hh*64;
  { // stage V 64x64 tile (row-major padded, coalesced reads)
    int row = tid >> 2, c16 = (tid & 3) * 16;
    const u16* sp = projh + (bS + t0 + row) * P_ + voff + c16;
    short8 a = *(const short8*)sp;
    short8 bq = *(const short8*)(sp + 8);
    *(short8*)&tls[row*72 + c16] = a;
    *(short8*)&tls[row*72 + c16 + 8] = bq;
  }
  __syncthreads();
  size_t obase = ((size_t)(bh*32 + t) * 8) * 512;
  #pragma unroll
  for (int pass = 0; pass < 2; pass++){
    int id = tid + pass * 256;          // 512 tasks: (c, lane)
    int c = id >> 6, lane = id & 63;
    int quad = lane >> 4, l15 = lane & 15;
    int cns = c >> 1, ckst = c & 1;
    const u16* kp = projh + (bS + t0 + cns*16 + l15) * P_ + koff + ckst*32 + quad*8;
    *(short8*)(kpack + obase + (size_t)c*512 + lane*8) = *(const short8*)kp;
    short8 vv;
    #pragma unroll
    for (int j = 0; j < 8; j++)
      vv[j] = (short)tls[(ckst*32 + quad*8 + j)*72 + cns*16 + l15];
    *(short8*)(vpack + obase + (size_t)c*512 + lane*8) = vv;
  }
}

// ---- LayerNorm over D=1024; one block per row ----
// bf16 path writes fragment-packed h (32 chunks x 256 mgroups); fp32 path row-major.
__global__ __launch_bounds__(256) void ln_kernel(const float* __restrict__ src,
    const float* __restrict__ w, const float* __restrict__ b,
    void* __restrict__ outp, float eps, int out_bf16){
  int row = blockIdx.x, tid = threadIdx.x;
  const float* xr = src + (size_t)row * D_;
  float4 v = *(const float4*)(xr + tid * 4);
  float s  = v.x + v.y + v.z + v.w;
  float sq = v.x*v.x + v.y*v.y + v.z*v.z + v.w*v.w;
  #pragma unroll
  for (int off = 32; off; off >>= 1){ s += __shfl_down(s, off); sq += __shfl_down(sq, off); }
  __shared__ float red[8];
  __shared__ float stats[2];
  int wid = tid >> 6;
  if ((tid & 63) == 0){ red[wid] = s; red[4 + wid] = sq; }
  __syncthreads();
  if (tid == 0){
    float S1 = red[0] + red[1] + red[2] + red[3];
    float S2 = red[4] + red[5] + red[6] + red[7];
    float mu = S1 * (1.0f / D_);
    float var = S2 * (1.0f / D_) - mu * mu;
    stats[0] = mu; stats[1] = rsqrtf(var + eps);
  }
  __syncthreads();
  float mu = stats[0], rs = stats[1];
  int i = tid * 4;
  float4 wv = *(const float4*)(w + i);
  float4 bv = *(const float4*)(b + i);
  float o0 = (v.x - mu) * rs * wv.x + bv.x;
  float o1 = (v.y - mu) * rs * wv.y + bv.y;
  float o2 = (v.z - mu) * rs * wv.z + bv.z;
  float o3 = (v.w - mu) * rs * wv.w + bv.w;
  if (out_bf16){
    ushort4 o; o.x = f2bfu(o0); o.y = f2bfu(o1); o.z = f2bfu(o2); o.w = f2bfu(o3);
    int mg = row >> 4, l15 = row & 15;
    int c = i >> 5, q = (i >> 3) & 3, j = i & 7;      // j in {0,4}
    *(ushort4*)((u16*)outp + ((size_t)(c*256 + mg))*512 + q*128 + l15*8 + j) = o;
  } else {
    *(float4*)((float*)outp + (size_t)row * D_ + i) = make_float4(o0, o1, o2, o3);
  }
}

// ---- barrier-free packed-register GEMM core (templated wave tile NIx16 x NJx16) ----
// Operands fragment-packed chunk-major; 16B/lane fully coalesced loads;
// 2-deep named register pipeline, no barriers, no LDS. Bit-identical
// accumulation order (chunks in sequence).
template<int KCH, int MGA, int MGB, int NI, int NJ>
__device__ __forceinline__ void gemm_pk_core(const u16* __restrict__ Ap,
    const u16* __restrict__ Bp, int mg0, int ng0, v4f (&acc)[NI][NJ]){
  int lane = threadIdx.x & 63;
  const u16* ap = Ap + (size_t)mg0*512 + lane*8;
  const u16* bp = Bp + (size_t)ng0*512 + lane*8;
  short8 aA[NI], bA[NJ], aB[NI], bB[NJ];
  auto LOADK = [&](short8 (&af)[NI], short8 (&bf)[NJ], int c){
    const u16* apc = ap + (size_t)c*MGA*512;
    const u16* bpc = bp + (size_t)c*MGB*512;
    #pragma unroll
    for (int i = 0; i < NI; i++) af[i] = *(const short8*)(apc + i*512);
    #pragma unroll
    for (int j = 0; j < NJ; j++) bf[j] = *(const short8*)(bpc + j*512);
  };
  auto COMP = [&](const short8 (&af)[NI], const short8 (&bf)[NJ]){
    #pragma unroll
    for (int i = 0; i < NI; i++)
      #pragma unroll
      for (int j = 0; j < NJ; j++)
        acc[i][j] = __builtin_amdgcn_mfma_f32_16x16x32_bf16(
            __builtin_bit_cast(bf16x8, af[i]), __builtin_bit_cast(bf16x8, bf[j]),
            acc[i][j], 0, 0, 0);
  };
  LOADK(aA, bA, 0);
  for (int c = 0; c < KCH; c += 2){          // KCH even
    LOADK(aB, bB, c + 1);
    COMP(aA, bA);
    if (c + 2 < KCH) LOADK(aA, bA, c + 2);
    COMP(aB, bB);
  }
}

// ---- projh = silu(h @ uvqk) -> bf16; 128x64 tiles (1024 blocks = 4/CU) ----
__global__ __launch_bounds__(256) void gemm_silu_mfma(const u16* __restrict__ A,
    const u16* __restrict__ Bt, u16* __restrict__ C){
  v4f acc[4][2];
  #pragma unroll
  for (int i = 0; i < 4; i++)
    #pragma unroll
    for (int j = 0; j < 2; j++) acc[i][j] = (v4f){0.f,0.f,0.f,0.f};
  // 1024 wgs = 32 by x 32 bx; XCD k owns an 8x16 (by,bx) subtile:
  // A 8 panels x 128 rows (2MB) + B 16 panels x 64 rows (2MB) L2-resident.
  int f = blockIdx.x;
  int k = f & 7, local = f >> 3;
  int by = (k & 3) * 8 + (local >> 4);
  int bx = (k >> 2) * 16 + (local & 15);
  int m0 = by * 128, n0 = bx * 64;
  int tid = threadIdx.x, w = tid >> 6, lane = tid & 63;
  int wm = w >> 1, wn = w & 1, quad = lane >> 4, l15 = lane & 15;
  gemm_pk_core<32, 256, 128, 4, 2>(A, Bt, (m0 >> 4) + wm*4, (n0 >> 4) + wn*2, acc);
  #pragma unroll
  for (int i = 0; i < 4; i++)
    #pragma unroll
    for (int r = 0; r < 4; r++){
      int m = m0 + wm*64 + i*16 + quad*4 + r;
      u16* cp = C + (size_t)m * P_ + n0 + wn*32 + l15;
      #pragma unroll
      for (int j = 0; j < 2; j++)
        cp[j*16] = f2bfu(silu_fast(acc[i][j][r]));
    }
}

// ---- Xout = Xin + udot @ owh^T + o_b; 64x64 tiles (1024 blocks = 4/CU) ----
__global__ __launch_bounds__(256) void gemm_add_mfma(const u16* __restrict__ A,
    const u16* __restrict__ Bt, const float* __restrict__ bias,
    const float* __restrict__ Xin, float* __restrict__ Xout){
  v4f acc[2][2];
  #pragma unroll
  for (int i = 0; i < 2; i++)
    #pragma unroll
    for (int j = 0; j < 2; j++) acc[i][j] = (v4f){0.f,0.f,0.f,0.f};
  // 1024 wgs = 64 by x 16 bx; XCD k owns a 16x8 (by,bx) subtile.
  int f = blockIdx.x;
  int k = f & 7, local = f >> 3;
  int by = (k & 3) * 16 + (local >> 3);
  int bx = (k >> 2) * 8 + (local & 7);
  int m0 = by * 64, n0 = bx * 64;
  int tid = threadIdx.x, w = tid >> 6, lane = tid & 63;
  int wm = w >> 1, wn = w & 1, quad = lane >> 4, l15 = lane & 15;
  gemm_pk_core<16, 256, 64, 2, 2>(A, Bt, (m0 >> 4) + wm*2, (n0 >> 4) + wn*2, acc);
  float bj[2];
  #pragma unroll
  for (int j = 0; j < 2; j++) bj[j] = bias[n0 + wn*32 + j*16 + l15];
  #pragma unroll
  for (int i = 0; i < 2; i++)
    #pragma unroll
    for (int r = 0; r < 4; r++){
      int m = m0 + wm*32 + i*16 + quad*4 + r;
      size_t off = (size_t)m * D_ + n0 + wn*32 + l15;
      const float* xi = Xin + off;
      float* xo = Xout + off;
      #pragma unroll
      for (int j = 0; j < 2; j++)
        xo[j*16] = xi[j*16] + acc[i][j][r] + bj[j];
    }
}

// ---- MFMA bf16 causal silu-attention, kt-split partials -> opart bf16 slices ----
// r5 grid/decode + r5 per-tile math, K/V B-frags global->register with 2-deep
// named register pipeline, zero barriers (verified R6).
__global__ __launch_bounds__(256) void attn_kernel(const u16* __restrict__ projh,
                                                   const u16* __restrict__ kpack,
                                                   const u16* __restrict__ vpack,
                                                   u16* __restrict__ opart){
  __shared__ u16 Ps[64*72];        // bf16 scores, wave-private 16-row bands, reused per qh
  int f = (int)blockIdx.x;         // flat 512
  int g = f & 7;                   // XCD group
  int s = f >> 3;                  // [0,64)
  int c = s & 31;                  // CU-local seq within group
  int slot = s >> 5;               // 0/1: first/second block on the CU
  int z = c >> 4;                  // kt-split 0..1
  int x = c & 15;
  int qt = slot ? x : (15 - x);    // complementary pairing
  int bh = g + (slot << 3);
  int ttop = 2*qt + 1;
  int b = bh >> 3, hh = bh & 7;
  int tid = threadIdx.x;
  int w = tid >> 6, lane = tid & 63, quad = lane >> 4, l15 = lane & 15;
  int s0 = qt * 128;
  const size_t bS = (size_t)b * S_;
  const int qoff = 2*F_ + hh*64;

  bf16x8 aq[2][2];
  #pragma unroll
  for (int qh = 0; qh < 2; qh++){
    const u16* qp = projh + (bS + s0 + qh*64 + w*16 + l15) * P_ + qoff + quad*8;
    aq[qh][0] = __builtin_bit_cast(bf16x8, *(const short8*)qp);
    aq[qh][1] = __builtin_bit_cast(bf16x8, *(const short8*)(qp + 32));
  }

  v4f oacc[2][4];
  #pragma unroll
  for (int qh = 0; qh < 2; qh++)
    #pragma unroll
    for (int i = 0; i < 4; i++) oacc[qh][i] = (v4f){0.f, 0.f, 0.f, 0.f};

  auto LOADT = [&](short8 (&BK)[4][2], short8 (&VF)[4][2], int tt){
    size_t pb = ((size_t)(bh*32 + tt) * 8) * 512;
    #pragma unroll
    for (int cc = 0; cc < 8; cc++){
      BK[cc>>1][cc&1] = *(const short8*)(kpack + pb + (size_t)cc*512 + lane*8);
      VF[cc>>1][cc&1] = *(const short8*)(vpack + pb + (size_t)cc*512 + lane*8);
    }
  };

  auto COMPUTE = [&](const short8 (&BK)[4][2], const short8 (&VF)[4][2], int t){
    #pragma unroll
    for (int qh = 0; qh < 2; qh++){
      int dtile = 2*qt + qh;
      if (t > dtile) continue;
      v4f sacc[4];
      #pragma unroll
      for (int i = 0; i < 4; i++) sacc[i] = (v4f){0.f, 0.f, 0.f, 0.f};
      #pragma unroll
      for (int ns = 0; ns < 4; ns++){
        sacc[ns] = __builtin_amdgcn_mfma_f32_16x16x32_bf16(aq[qh][0],
            __builtin_bit_cast(bf16x8, BK[ns][0]), sacc[ns], 0, 0, 0);
        sacc[ns] = __builtin_amdgcn_mfma_f32_16x16x32_bf16(aq[qh][1],
            __builtin_bit_cast(bf16x8, BK[ns][1]), sacc[ns], 0, 0, 0);
      }
      bool diag = (t == dtile);
      #pragma unroll
      for (int ns = 0; ns < 4; ns++){
        #pragma unroll
        for (int r = 0; r < 4; r++){
          int rl = w*16 + quad*4 + r;
          int cl = ns*16 + l15;
          float p = silu_fast(sacc[ns][r]) * (1.0f / S_);
          if (diag && cl > rl) p = 0.0f;
          Ps[rl*72 + cl] = f2bfu(p);
        }
      }
      // wave-private bf16 readback = PV A-frag (in-order per-wave LDS)
      #pragma unroll
      for (int kst = 0; kst < 2; kst++){
        short8 aps = *(const short8*)&Ps[(w*16 + l15)*72 + kst*32 + quad*8];
        bf16x8 ap = __builtin_bit_cast(bf16x8, aps);
        #pragma unroll
        for (int ds = 0; ds < 4; ds++)
          oacc[qh][ds] = __builtin_amdgcn_mfma_f32_16x16x32_bf16(
              ap, __builtin_bit_cast(bf16x8, VF[ds][kst]), oacc[qh][ds], 0, 0, 0);
      }
    }
  };

  // 2-deep register pipeline over tiles t = z, z+2, ..., ttop (named bufs A/B)
  short8 kA[4][2], vA[4][2], kB[4][2], vB[4][2];
  int t = z;
  LOADT(kA, vA, t);
  for (;;){
    if (t + 2 <= ttop){
      LOADT(kB, vB, t + 2);
      COMPUTE(kA, vA, t);
      t += 2;
    } else {
      COMPUTE(kA, vA, t);
      break;
    }
    if (t + 2 <= ttop){
      LOADT(kA, vA, t + 2);
      COMPUTE(kB, vB, t);
      t += 2;
    } else {
      COMPUTE(kB, vB, t);
      break;
    }
  }

  // epilogue: plain bf16 stores of raw O partials into this z's private slice.
  u16* ob = opart + (size_t)z * ((size_t)R_ * F_);
  #pragma unroll
  for (int qh = 0; qh < 2; qh++){
    #pragma unroll
    for (int r = 0; r < 4; r++){
      int sg = s0 + qh*64 + w*16 + quad*4 + r;
      u16* op = ob + (bS + sg) * (size_t)F_ + hh*64 + l15;
      #pragma unroll
      for (int ds = 0; ds < 4; ds++)
        op[ds*16] = f2bfu(oacc[qh][ds][r]);
    }
  }
}

// ---- 64-dim no-affine norm + u-gate: sum of 2 bf16 opart slices -> udot ----
// udot is written fragment-packed (16 chunks x 256 mgroups) for gemm_add.
__global__ __launch_bounds__(256) void norm_gate_kernel(const u16* __restrict__ opart,
    const u16* __restrict__ projh, u16* __restrict__ udot){
  int w = threadIdx.x >> 6, lane = threadIdx.x & 63;
  int sg = blockIdx.x * 4 + w;
  int hh = lane >> 3, seg = lane & 7;
  size_t off = (size_t)sg * F_ + hh*64 + seg*8;
  short8 a0 = *(const short8*)(opart + off);
  short8 a1 = *(const short8*)(opart + (size_t)R_ * F_ + off);
  float e[8];
  float s = 0.f, sq = 0.f;
  #pragma unroll
  for (int i = 0; i < 8; i++){
    e[i] = bf2f((u16)a0[i]) + bf2f((u16)a1[i]);
    s += e[i]; sq += e[i]*e[i];
  }
  #pragma unroll
  for (int m = 1; m < 8; m <<= 1){
    s  += __shfl_xor(s, m, 64);
    sq += __shfl_xor(sq, m, 64);
  }
  float mu = s * (1.0f/64.0f);
  float var = sq * (1.0f/64.0f) - mu*mu;
  float rs = rsqrtf(var + 1e-6f);
  const u16* up = projh + (size_t)sg * P_ + hh*64 + seg*8;
  short8 uv = *(const short8*)up;
  short8 ov;
  #pragma unroll
  for (int i = 0; i < 8; i++)
    ov[i] = (short)f2bfu((e[i] - mu) * rs * bf2f((u16)uv[i]));
  // packed write: d0 = hh*64+seg*8 -> chunk c = hh*2+(seg>>2), quad q = seg&3
  int mg = sg >> 4, l15 = sg & 15;
  int c = hh*2 + (seg >> 2), q = seg & 3;
  *(short8*)(udot + ((size_t)(c*256 + mg))*512 + q*128 + l15*8) = ov;
}

extern "C" void kernel_launch(void* const* d_in, const int* in_sizes, int n_in,
                              void* d_out, int out_size, void* d_ws, size_t ws_size,
                              hipStream_t stream){
  (void)in_sizes; (void)n_in; (void)out_size; (void)ws_size;
  const float* x     = (const float*)d_in[0];
  // d_in[1] = attn_mask (causal tril) -- hardcoded
  const float* uvqk  = (const float*)d_in[2];
  const float* o_w   = (const float*)d_in[3];
  const float* o_b   = (const float*)d_in[4];
  const float* ln_w  = (const float*)d_in[5];
  const float* ln_b  = (const float*)d_in[6];
  const float* lln_w = (const float*)d_in[7];
  const float* lln_b = (const float*)d_in[8];
  float* out = (float*)d_out;

  char* ws = (char*)d_ws;
  float* xf    = (float*)ws;                          // 16 MB
  u16*   h     = (u16*)(ws + (16u<<20));              //  8 MB (ln out, packed)
  u16*   kpack = h;                                   //  4 MB alias (h dead after gemm_silu)
  u16*   vpack = (u16*)(ws + (20u<<20));              //  4 MB alias
  u16*   udot  = (u16*)(ws + (24u<<20));              //  4 MB (packed)
  u16*   projh = (u16*)(ws + (28u<<20));              // 16 MB
  u16*   uvqkT = (u16*)(ws + (44u<<20));              //  8 MB (packed)
  u16*   owh   = (u16*)(ws + (52u<<20));              //  2 MB (packed)
  u16*   opart = (u16*)(ws + (54u<<20));              //  8 MB (2 bf16 z-slices)

  cvt_uvqkT_kernel<<<dim3(P_/32, D_/32, L_), 256, 0, stream>>>(uvqk, uvqkT);
  cvt_owh_kernel<<<L_ * D_ * F_ / 1024, 256, 0, stream>>>(o_w, owh);
  for (int l = 0; l < L_; l++){
    // layer 0 reads residual stream from x; xf is first written by layer-0
    // gemm_add (out-of-place) and carries the stream from then on.
    const float* xsrc = (l == 0) ? x : xf;
    ln_kernel<<<R_, 256, 0, stream>>>(xsrc, ln_w + l * D_, ln_b + l * D_, h, 1e-6f, 1);
    gemm_silu_mfma<<<1024, 256, 0, stream>>>(
        h, uvqkT + (size_t)l * P_ * D_, projh);
    kvpack_kernel<<<dim3(S_/64, B_*H_), 256, 0, stream>>>(projh, kpack, vpack);
    attn_kernel<<<512, 256, 0, stream>>>(projh, kpack, vpack, opart);
    norm_gate_kernel<<<R_/4, 256, 0, stream>>>(opart, projh, udot);
    gemm_add_mfma<<<1024, 256, 0, stream>>>(
        udot, owh + (size_t)l * D_ * F_, o_b + l * D_, xsrc, xf);
  }
  ln_kernel<<<R_, 256, 0, stream>>>(xf, lln_w, lln_b, out, 1e-8f, 0);
}

// Round 11
// 291.590 us; speedup vs baseline: 1.0341x; 1.0341x over previous
//
#include <hip/hip_runtime.h>

// HSTU block, B=2 S=2048 D=1024 H=8 head=64 L=2. Inputs/outputs fp32.
// ws (62 MB): xf f32(16M) | h bf16(8M; aliased by kpack 4M + vpack 4M)
//  | udot bf16(4M) | projh bf16(16M) | uvqkT bf16(8M) | owh bf16(2M)
//  | opart bf16 2 z-slices (8M)
#define B_ 2
#define S_ 2048
#define D_ 1024
#define H_ 8
#define L_ 2
#define P_ 2048   // proj dim
#define F_ 512    // DL*H
#define R_ (B_*S_)

typedef unsigned short u16;
typedef unsigned int u32;
typedef __bf16 bf16;
typedef bf16 bf16x8 __attribute__((ext_vector_type(8)));
typedef short short8 __attribute__((ext_vector_type(8)));
typedef float v4f __attribute__((ext_vector_type(4)));

__device__ __forceinline__ float silu_fast(float x){
  float e = __expf(-x);
  return x * __builtin_amdgcn_rcpf(1.0f + e);
}
__device__ __forceinline__ float bf2f(u16 u){
  union { u32 i; float f; } x; x.i = ((u32)u) << 16; return x.f;
}
__device__ __forceinline__ u16 f2bfu(float f){
  union { float f; u32 i; } x; x.f = f;
  u32 r = x.i + 0x7fff + ((x.i >> 16) & 1);   // RNE
  return (u16)(r >> 16);
}
__device__ __forceinline__ void gload16(const u16* g, u16* l){
  __builtin_amdgcn_global_load_lds(
      (const __attribute__((address_space(1))) void*)g,
      (__attribute__((address_space(3))) void*)l, 16, 0, 0);
}

// ---- fp32 -> bf16 elementwise (o_w) ----
__global__ __launch_bounds__(256) void cvt_bf16_kernel(const float* __restrict__ src, u16* __restrict__ dst){
  int i = (blockIdx.x * 256 + threadIdx.x) * 4;
  float4 v = *(const float4*)(src + i);
  ushort4 o; o.x = f2bfu(v.x); o.y = f2bfu(v.y); o.z = f2bfu(v.z); o.w = f2bfu(v.w);
  *(ushort4*)(dst + i) = o;
}

// ---- uvqk (L,D,P) f32 -> uvqkT (L,P,D) bf16 ----
__global__ __launch_bounds__(256) void cvt_uvqkT_kernel(const float* __restrict__ uvqk, u16* __restrict__ ot){
  __shared__ float t[32][33];
  int l = blockIdx.z;
  int p0 = blockIdx.x * 32, d0 = blockIdx.y * 32;
  int tx = threadIdx.x & 31, ty = threadIdx.x >> 5;   // ty: 8 rows/pass
  const float* src = uvqk + ((size_t)l * D_ + d0) * P_ + p0;
  #pragma unroll
  for (int s = 0; s < 4; s++)
    t[ty + s*8][tx] = src[(size_t)(ty + s*8) * P_ + tx];
  __syncthreads();
  u16* dst = ot + ((size_t)l * P_ + p0) * D_ + d0;
  #pragma unroll
  for (int s = 0; s < 4; s++)
    dst[(size_t)(ty + s*8) * D_ + tx] = f2bfu(t[tx][ty + s*8]);
}

// ---- pack K and V tiles into fragment-linear order ----
__global__ __launch_bounds__(256) void kvpack_kernel(const u16* __restrict__ projh,
    u16* __restrict__ kpack, u16* __restrict__ vpack){
  __shared__ u16 tls[64*72];
  int t = blockIdx.x, t0 = t * 64;
  int bh = blockIdx.y;
  int b = bh >> 3, hh = bh & 7;
  int tid = threadIdx.x;
  const size_t bS = (size_t)b * S_;
  const int voff = F_ + hh*64, koff = 3*F_ + hh*64;
  { // stage V 64x64 tile (row-major padded, coalesced reads)
    int row = tid >> 2, c16 = (tid & 3) * 16;
    const u16* sp = projh + (bS + t0 + row) * P_ + voff + c16;
    short8 a = *(const short8*)sp;
    short8 bq = *(const short8*)(sp + 8);
    *(short8*)&tls[row*72 + c16] = a;
    *(short8*)&tls[row*72 + c16 + 8] = bq;
  }
  __syncthreads();
  size_t obase = ((size_t)(bh*32 + t) * 8) * 512;
  #pragma unroll
  for (int pass = 0; pass < 2; pass++){
    int id = tid + pass * 256;          // 512 tasks: (c, lane)
    int c = id >> 6, lane = id & 63;
    int quad = lane >> 4, l15 = lane & 15;
    int cns = c >> 1, ckst = c & 1;
    const u16* kp = projh + (bS + t0 + cns*16 + l15) * P_ + koff + ckst*32 + quad*8;
    *(short8*)(kpack + obase + (size_t)c*512 + lane*8) = *(const short8*)kp;
    short8 vv;
    #pragma unroll
    for (int j = 0; j < 8; j++)
      vv[j] = (short)tls[(ckst*32 + quad*8 + j)*72 + cns*16 + l15];
    *(short8*)(vpack + obase + (size_t)c*512 + lane*8) = vv;
  }
}

// ---- LayerNorm over D=1024; one block per row; bf16 or fp32 out ----
__global__ __launch_bounds__(256) void ln_kernel(const float* __restrict__ src,
    const float* __restrict__ w, const float* __restrict__ b,
    void* __restrict__ outp, float eps, int out_bf16){
  int row = blockIdx.x, tid = threadIdx.x;
  const float* xr = src + (size_t)row * D_;
  float4 v = *(const float4*)(xr + tid * 4);
  float s  = v.x + v.y + v.z + v.w;
  float sq = v.x*v.x + v.y*v.y + v.z*v.z + v.w*v.w;
  #pragma unroll
  for (int off = 32; off; off >>= 1){ s += __shfl_down(s, off); sq += __shfl_down(sq, off); }
  __shared__ float red[8];
  __shared__ float stats[2];
  int wid = tid >> 6;
  if ((tid & 63) == 0){ red[wid] = s; red[4 + wid] = sq; }
  __syncthreads();
  if (tid == 0){
    float S1 = red[0] + red[1] + red[2] + red[3];
    float S2 = red[4] + red[5] + red[6] + red[7];
    float mu = S1 * (1.0f / D_);
    float var = S2 * (1.0f / D_) - mu * mu;
    stats[0] = mu; stats[1] = rsqrtf(var + eps);
  }
  __syncthreads();
  float mu = stats[0], rs = stats[1];
  int i = tid * 4;
  float4 wv = *(const float4*)(w + i);
  float4 bv = *(const float4*)(b + i);
  float o0 = (v.x - mu) * rs * wv.x + bv.x;
  float o1 = (v.y - mu) * rs * wv.y + bv.y;
  float o2 = (v.z - mu) * rs * wv.z + bv.z;
  float o3 = (v.w - mu) * rs * wv.w + bv.w;
  if (out_bf16){
    ushort4 o; o.x = f2bfu(o0); o.y = f2bfu(o1); o.z = f2bfu(o2); o.w = f2bfu(o3);
    *(ushort4*)((u16*)outp + (size_t)row * D_ + i) = o;
  } else {
    *(float4*)((float*)outp + (size_t)row * D_ + i) = make_float4(o0, o1, o2, o3);
  }
}

// ---- MFMA GEMM core (LDS-staged, R6-verified dataflow), templated tile ----
// GA/GB = 16-row groups in A/B tile; NI/NJ = per-wave row/col fragments.
// Wave (wm,wn) owns rows wm*(NI*16).., cols wn*(NJ*16)..; staging identical
// to the verified core (gload16, wave-uniform LDS base + per-lane global).
// Accumulation order per output element unchanged -> bit-identical results.
template<int KDIM, int GA, int GB, int NI, int NJ>
__device__ __forceinline__ void gemm_mfma_core(const u16* __restrict__ A,
    const u16* __restrict__ Bt, u16* As, u16* Bs, int m0, int n0,
    v4f (&acc)[NI][NJ]){
  int tid = threadIdx.x;
  int w = tid >> 6, lane = tid & 63;
  int wm = w >> 1, wn = w & 1, quad = lane >> 4, l15 = lane & 15;
  int srow = lane >> 2, skoct = (lane & 3) * 8;
  for (int kt = 0; kt < KDIM; kt += 32){
    __syncthreads();
    #pragma unroll
    for (int g = 0; g < GA/4; g++)
      gload16(A + (size_t)(m0 + (w + g*4)*16 + srow) * KDIM + kt + skoct,
              As + (w + g*4)*512);
    #pragma unroll
    for (int g = 0; g < GB/4; g++)
      gload16(Bt + (size_t)(n0 + (w + g*4)*16 + srow) * KDIM + kt + skoct,
              Bs + (w + g*4)*512);
    __syncthreads();
    short8 af[NI], bfr[NJ];
    #pragma unroll
    for (int i = 0; i < NI; i++)
      af[i] = *(const short8*)&As[(wm*(NI*16) + i*16 + l15)*32 + quad*8];
    #pragma unroll
    for (int j = 0; j < NJ; j++)
      bfr[j] = *(const short8*)&Bs[(wn*(NJ*16) + j*16 + l15)*32 + quad*8];
    #pragma unroll
    for (int i = 0; i < NI; i++)
      #pragma unroll
      for (int j = 0; j < NJ; j++)
        acc[i][j] = __builtin_amdgcn_mfma_f32_16x16x32_bf16(
            __builtin_bit_cast(bf16x8, af[i]), __builtin_bit_cast(bf16x8, bfr[j]),
            acc[i][j], 0, 0, 0);
  }
}

// ---- projh = silu(h @ uvqk) -> bf16; 128x64 tiles, 1024 blocks = 4/CU ----
__global__ __launch_bounds__(256) void gemm_silu_mfma(const u16* __restrict__ A,
    const u16* __restrict__ Bt, u16* __restrict__ C){
  __shared__ u16 As[128*32], Bs[64*32];
  v4f acc[4][2];
  #pragma unroll
  for (int i = 0; i < 4; i++)
    #pragma unroll
    for (int j = 0; j < 2; j++) acc[i][j] = (v4f){0.f,0.f,0.f,0.f};
  // 1024 wgs = 32 by x 32 bx; XCD k owns 8 by x 16 bx:
  // A 8x128 rows (2MB) + B 16x64 rows (2MB) L2-resident.
  int f = blockIdx.x;
  int k = f & 7, local = f >> 3;
  int by = (k & 3) * 8 + (local >> 4);
  int bx = (k >> 2) * 16 + (local & 15);
  int m0 = by * 128, n0 = bx * 64;
  gemm_mfma_core<D_, 8, 4, 4, 2>(A, Bt, As, Bs, m0, n0, acc);
  int tid = threadIdx.x, w = tid >> 6, lane = tid & 63;
  int wm = w >> 1, wn = w & 1, quad = lane >> 4, l15 = lane & 15;
  #pragma unroll
  for (int i = 0; i < 4; i++)
    #pragma unroll
    for (int r = 0; r < 4; r++){
      int m = m0 + wm*64 + i*16 + quad*4 + r;
      u16* cp = C + (size_t)m * P_ + n0 + wn*32 + l15;
      #pragma unroll
      for (int j = 0; j < 2; j++)
        cp[j*16] = f2bfu(silu_fast(acc[i][j][r]));
    }
}

// ---- Xout = Xin + udot @ owh^T + o_b; 64x64 tiles, 1024 blocks = 4/CU ----
__global__ __launch_bounds__(256) void gemm_add_mfma(const u16* __restrict__ A,
    const u16* __restrict__ Bt, const float* __restrict__ bias,
    const float* __restrict__ Xin, float* __restrict__ Xout){
  __shared__ u16 As[64*32], Bs[64*32];
  v4f acc[2][2];
  #pragma unroll
  for (int i = 0; i < 2; i++)
    #pragma unroll
    for (int j = 0; j < 2; j++) acc[i][j] = (v4f){0.f,0.f,0.f,0.f};
  // 1024 wgs = 64 by x 16 bx; XCD k owns 16 by x 8 bx (A 1MB + B 0.5MB).
  int f = blockIdx.x;
  int k = f & 7, local = f >> 3;
  int by = (k & 3) * 16 + (local >> 3);
  int bx = (k >> 2) * 8 + (local & 7);
  int m0 = by * 64, n0 = bx * 64;
  gemm_mfma_core<F_, 4, 4, 2, 2>(A, Bt, As, Bs, m0, n0, acc);
  int tid = threadIdx.x, w = tid >> 6, lane = tid & 63;
  int wm = w >> 1, wn = w & 1, quad = lane >> 4, l15 = lane & 15;
  float bj[2];
  #pragma unroll
  for (int j = 0; j < 2; j++) bj[j] = bias[n0 + wn*32 + j*16 + l15];
  #pragma unroll
  for (int i = 0; i < 2; i++)
    #pragma unroll
    for (int r = 0; r < 4; r++){
      int m = m0 + wm*32 + i*16 + quad*4 + r;
      size_t off = (size_t)m * D_ + n0 + wn*32 + l15;
      const float* xi = Xin + off;
      float* xo = Xout + off;
      #pragma unroll
      for (int j = 0; j < 2; j++)
        xo[j*16] = xi[j*16] + acc[i][j][r] + bj[j];
    }
}

// ---- MFMA bf16 causal silu-attention, kt-split partials -> opart bf16 slices ----
// R6-verified: flat 512 grid (XCD grouping + complementary pairing), K/V
// B-frags global->register, 2-deep named register pipeline, zero barriers.
__global__ __launch_bounds__(256) void attn_kernel(const u16* __restrict__ projh,
                                                   const u16* __restrict__ kpack,
                                                   const u16* __restrict__ vpack,
                                                   u16* __restrict__ opart){
  __shared__ u16 Ps[64*72];        // bf16 scores, wave-private 16-row bands, reused per qh
  int f = (int)blockIdx.x;         // flat 512
  int g = f & 7;                   // XCD group
  int s = f >> 3;                  // [0,64)
  int c = s & 31;                  // CU-local seq within group
  int slot = s >> 5;               // 0/1: first/second block on the CU
  int z = c >> 4;                  // kt-split 0..1
  int x = c & 15;
  int qt = slot ? x : (15 - x);    // complementary pairing
  int bh = g + (slot << 3);
  int ttop = 2*qt + 1;
  int b = bh >> 3, hh = bh & 7;
  int tid = threadIdx.x;
  int w = tid >> 6, lane = tid & 63, quad = lane >> 4, l15 = lane & 15;
  int s0 = qt * 128;
  const size_t bS = (size_t)b * S_;
  const int qoff = 2*F_ + hh*64;

  bf16x8 aq[2][2];
  #pragma unroll
  for (int qh = 0; qh < 2; qh++){
    const u16* qp = projh + (bS + s0 + qh*64 + w*16 + l15) * P_ + qoff + quad*8;
    aq[qh][0] = __builtin_bit_cast(bf16x8, *(const short8*)qp);
    aq[qh][1] = __builtin_bit_cast(bf16x8, *(const short8*)(qp + 32));
  }

  v4f oacc[2][4];
  #pragma unroll
  for (int qh = 0; qh < 2; qh++)
    #pragma unroll
    for (int i = 0; i < 4; i++) oacc[qh][i] = (v4f){0.f, 0.f, 0.f, 0.f};

  auto LOADT = [&](short8 (&BK)[4][2], short8 (&VF)[4][2], int tt){
    size_t pb = ((size_t)(bh*32 + tt) * 8) * 512;
    #pragma unroll
    for (int cc = 0; cc < 8; cc++){
      BK[cc>>1][cc&1] = *(const short8*)(kpack + pb + (size_t)cc*512 + lane*8);
      VF[cc>>1][cc&1] = *(const short8*)(vpack + pb + (size_t)cc*512 + lane*8);
    }
  };

  auto COMPUTE = [&](const short8 (&BK)[4][2], const short8 (&VF)[4][2], int t){
    #pragma unroll
    for (int qh = 0; qh < 2; qh++){
      int dtile = 2*qt + qh;
      if (t > dtile) continue;
      v4f sacc[4];
      #pragma unroll
      for (int i = 0; i < 4; i++) sacc[i] = (v4f){0.f, 0.f, 0.f, 0.f};
      #pragma unroll
      for (int ns = 0; ns < 4; ns++){
        sacc[ns] = __builtin_amdgcn_mfma_f32_16x16x32_bf16(aq[qh][0],
            __builtin_bit_cast(bf16x8, BK[ns][0]), sacc[ns], 0, 0, 0);
        sacc[ns] = __builtin_amdgcn_mfma_f32_16x16x32_bf16(aq[qh][1],
            __builtin_bit_cast(bf16x8, BK[ns][1]), sacc[ns], 0, 0, 0);
      }
      bool diag = (t == dtile);
      #pragma unroll
      for (int ns = 0; ns < 4; ns++){
        #pragma unroll
        for (int r = 0; r < 4; r++){
          int rl = w*16 + quad*4 + r;
          int cl = ns*16 + l15;
          float p = silu_fast(sacc[ns][r]) * (1.0f / S_);
          if (diag && cl > rl) p = 0.0f;
          Ps[rl*72 + cl] = f2bfu(p);
        }
      }
      // wave-private bf16 readback = PV A-frag (in-order per-wave LDS)
      #pragma unroll
      for (int kst = 0; kst < 2; kst++){
        short8 aps = *(const short8*)&Ps[(w*16 + l15)*72 + kst*32 + quad*8];
        bf16x8 ap = __builtin_bit_cast(bf16x8, aps);
        #pragma unroll
        for (int ds = 0; ds < 4; ds++)
          oacc[qh][ds] = __builtin_amdgcn_mfma_f32_16x16x32_bf16(
              ap, __builtin_bit_cast(bf16x8, VF[ds][kst]), oacc[qh][ds], 0, 0, 0);
      }
    }
  };

  // 2-deep register pipeline over tiles t = z, z+2, ..., ttop (named bufs A/B)
  short8 kA[4][2], vA[4][2], kB[4][2], vB[4][2];
  int t = z;
  LOADT(kA, vA, t);
  for (;;){
    if (t + 2 <= ttop){
      LOADT(kB, vB, t + 2);
      COMPUTE(kA, vA, t);
      t += 2;
    } else {
      COMPUTE(kA, vA, t);
      break;
    }
    if (t + 2 <= ttop){
      LOADT(kA, vA, t + 2);
      COMPUTE(kB, vB, t);
      t += 2;
    } else {
      COMPUTE(kB, vB, t);
      break;
    }
  }

  // epilogue: plain bf16 stores of raw O partials into this z's private slice.
  u16* ob = opart + (size_t)z * ((size_t)R_ * F_);
  #pragma unroll
  for (int qh = 0; qh < 2; qh++){
    #pragma unroll
    for (int r = 0; r < 4; r++){
      int sg = s0 + qh*64 + w*16 + quad*4 + r;
      u16* op = ob + (bS + sg) * (size_t)F_ + hh*64 + l15;
      #pragma unroll
      for (int ds = 0; ds < 4; ds++)
        op[ds*16] = f2bfu(oacc[qh][ds][r]);
    }
  }
}

// ---- 64-dim no-affine norm + u-gate: sum of 2 bf16 opart slices -> udot bf16 ----
__global__ __launch_bounds__(256) void norm_gate_kernel(const u16* __restrict__ opart,
    const u16* __restrict__ projh, u16* __restrict__ udot){
  int w = threadIdx.x >> 6, lane = threadIdx.x & 63;
  int sg = blockIdx.x * 4 + w;
  int hh = lane >> 3, seg = lane & 7;
  size_t off = (size_t)sg * F_ + hh*64 + seg*8;
  short8 a0 = *(const short8*)(opart + off);
  short8 a1 = *(const short8*)(opart + (size_t)R_ * F_ + off);
  float e[8];
  float s = 0.f, sq = 0.f;
  #pragma unroll
  for (int i = 0; i < 8; i++){
    e[i] = bf2f((u16)a0[i]) + bf2f((u16)a1[i]);
    s += e[i]; sq += e[i]*e[i];
  }
  #pragma unroll
  for (int m = 1; m < 8; m <<= 1){
    s  += __shfl_xor(s, m, 64);
    sq += __shfl_xor(sq, m, 64);
  }
  float mu = s * (1.0f/64.0f);
  float var = sq * (1.0f/64.0f) - mu*mu;
  float rs = rsqrtf(var + 1e-6f);
  const u16* up = projh + (size_t)sg * P_ + hh*64 + seg*8;
  short8 uv = *(const short8*)up;
  short8 ov;
  #pragma unroll
  for (int i = 0; i < 8; i++)
    ov[i] = (short)f2bfu((e[i] - mu) * rs * bf2f((u16)uv[i]));
  *(short8*)(udot + off) = ov;
}

extern "C" void kernel_launch(void* const* d_in, const int* in_sizes, int n_in,
                              void* d_out, int out_size, void* d_ws, size_t ws_size,
                              hipStream_t stream){
  (void)in_sizes; (void)n_in; (void)out_size; (void)ws_size;
  const float* x     = (const float*)d_in[0];
  // d_in[1] = attn_mask (causal tril) -- hardcoded
  const float* uvqk  = (const float*)d_in[2];
  const float* o_w   = (const float*)d_in[3];
  const float* o_b   = (const float*)d_in[4];
  const float* ln_w  = (const float*)d_in[5];
  const float* ln_b  = (const float*)d_in[6];
  const float* lln_w = (const float*)d_in[7];
  const float* lln_b = (const float*)d_in[8];
  float* out = (float*)d_out;

  char* ws = (char*)d_ws;
  float* xf    = (float*)ws;                          // 16 MB
  u16*   h     = (u16*)(ws + (16u<<20));              //  8 MB (ln out)
  u16*   kpack = h;                                   //  4 MB alias (h dead after gemm_silu)
  u16*   vpack = (u16*)(ws + (20u<<20));              //  4 MB alias
  u16*   udot  = (u16*)(ws + (24u<<20));              //  4 MB
  u16*   projh = (u16*)(ws + (28u<<20));              // 16 MB
  u16*   uvqkT = (u16*)(ws + (44u<<20));              //  8 MB
  u16*   owh   = (u16*)(ws + (52u<<20));              //  2 MB
  u16*   opart = (u16*)(ws + (54u<<20));              //  8 MB (2 bf16 z-slices)

  cvt_uvqkT_kernel<<<dim3(P_/32, D_/32, L_), 256, 0, stream>>>(uvqk, uvqkT);
  cvt_bf16_kernel<<<L_ * D_ * F_ / 1024, 256, 0, stream>>>(o_w, owh);
  for (int l = 0; l < L_; l++){
    // layer 0 reads residual stream from x; xf is first written by layer-0
    // gemm_add (out-of-place) and carries the stream from then on.
    const float* xsrc = (l == 0) ? x : xf;
    ln_kernel<<<R_, 256, 0, stream>>>(xsrc, ln_w + l * D_, ln_b + l * D_, h, 1e-6f, 1);
    gemm_silu_mfma<<<1024, 256, 0, stream>>>(
        h, uvqkT + (size_t)l * P_ * D_, projh);
    kvpack_kernel<<<dim3(S_/64, B_*H_), 256, 0, stream>>>(projh, kpack, vpack);
    attn_kernel<<<512, 256, 0, stream>>>(projh, kpack, vpack, opart);
    norm_gate_kernel<<<R_/4, 256, 0, stream>>>(opart, projh, udot);
    gemm_add_mfma<<<1024, 256, 0, stream>>>(
        udot, owh + (size_t)l * D_ * F_, o_b + l * D_, xsrc, xf);
  }
  ln_kernel<<<R_, 256, 0, stream>>>(xf, lln_w, lln_b, out, 1e-8f, 0);
}